// Round 1
// baseline (779.465 us; speedup 1.0000x reference)
//
#include <hip/hip_runtime.h>
#include <hip/hip_bf16.h>

// SpMM: out[row[e], :] += values[e] * b[col[e], :]
// N=100000, E=3200000, D=64, fp32.
// Round 0: one wave per edge, lane d handles column d. atomicAdd scatter.

#define D 64

__global__ __launch_bounds__(256) void spmm_atomic_kernel(
    const int* __restrict__ rows,   // indices[0], E elems
    const int* __restrict__ cols,   // indices[1], E elems
    const float* __restrict__ vals, // E elems
    const float* __restrict__ b,    // N x D
    float* __restrict__ out,        // N x D
    int E) {
    long long gid = (long long)blockIdx.x * blockDim.x + threadIdx.x;
    int e = (int)(gid >> 6);
    int d = (int)(gid & 63);
    if (e >= E) return;
    int r = rows[e];  // wave-uniform broadcast load
    int c = cols[e];
    float v = vals[e];
    float bv = b[(long long)c * D + d];   // coalesced 256B row read
    atomicAdd(&out[(long long)r * D + d], v * bv);  // coalesced scatter-add
}

extern "C" void kernel_launch(void* const* d_in, const int* in_sizes, int n_in,
                              void* d_out, int out_size, void* d_ws, size_t ws_size,
                              hipStream_t stream) {
    const int* indices = (const int*)d_in[0];   // (2, E) int32
    const float* vals  = (const float*)d_in[1]; // (E,)
    // d_in[2] is `shape` scalar (N) — known constant here
    const float* b     = (const float*)d_in[3]; // (N, D)

    int E = in_sizes[1];
    const int* rows = indices;
    const int* cols = indices + E;

    // Zero the output (harness poisons with 0xAA before every launch).
    hipMemsetAsync(d_out, 0, (size_t)out_size * sizeof(float), stream);

    long long total_threads = (long long)E * 64;
    int block = 256;
    int grid = (int)((total_threads + block - 1) / block);
    spmm_atomic_kernel<<<grid, block, 0, stream>>>(rows, cols, vals, b,
                                                   (float*)d_out, E);
}

// Round 2
// 568.443 us; speedup vs baseline: 1.3712x; 1.3712x over previous
//
#include <hip/hip_runtime.h>
#include <hip/hip_bf16.h>

// SpMM: out[row[e], :] += values[e] * b[col[e], :]
// N=100000, E=3200000, D=64, fp32.
// Round 1: on-the-fly counting sort by row -> CSR, then one wave per row,
// register accumulation, single write per output element. Removes the 205M
// memory-side atomics (round 0: WRITE_SIZE=800MB write-through) entirely.

#define D 64

// ---------------- fallback (round-0) path, used only if ws too small -------
__global__ __launch_bounds__(256) void spmm_atomic_kernel(
    const int* __restrict__ rows, const int* __restrict__ cols,
    const float* __restrict__ vals, const float* __restrict__ b,
    float* __restrict__ out, int E) {
  long long gid = (long long)blockIdx.x * blockDim.x + threadIdx.x;
  int e = (int)(gid >> 6);
  int d = (int)(gid & 63);
  if (e >= E) return;
  int r = rows[e];
  int c = cols[e];
  float v = vals[e];
  atomicAdd(&out[(long long)r * D + d], v * b[(long long)c * D + d]);
}

// ---------------- pass 1: histogram of rows --------------------------------
__global__ __launch_bounds__(256) void hist_kernel(
    const int* __restrict__ rows, int* __restrict__ counts, int E) {
  int e = blockIdx.x * blockDim.x + threadIdx.x;
  if (e < E) atomicAdd(&counts[rows[e]], 1);
}

// ---------------- pass 2: two-level exclusive scan over counts -------------
// level 1: inclusive scan of 512-element chunks + per-block sums
__global__ __launch_bounds__(512) void scan_blocks_kernel(
    const int* __restrict__ counts, int* __restrict__ incl,
    int* __restrict__ bsums, int n) {
  __shared__ int s[512];
  int i = blockIdx.x * 512 + threadIdx.x;
  int v = (i < n) ? counts[i] : 0;
  s[threadIdx.x] = v;
  __syncthreads();
  for (int off = 1; off < 512; off <<= 1) {
    int t = (threadIdx.x >= (unsigned)off) ? s[threadIdx.x - off] : 0;
    __syncthreads();
    s[threadIdx.x] += t;
    __syncthreads();
  }
  if (i < n) incl[i] = s[threadIdx.x];
  if (threadIdx.x == 511) bsums[blockIdx.x] = s[511];
}

// level 2: exclusive scan of block sums (single block, nb <= 256)
__global__ __launch_bounds__(256) void scan_sums_kernel(
    int* __restrict__ bsums, int nb) {
  __shared__ int s[256];
  int v = (threadIdx.x < (unsigned)nb) ? bsums[threadIdx.x] : 0;
  s[threadIdx.x] = v;
  __syncthreads();
  for (int off = 1; off < 256; off <<= 1) {
    int t = (threadIdx.x >= (unsigned)off) ? s[threadIdx.x - off] : 0;
    __syncthreads();
    s[threadIdx.x] += t;
    __syncthreads();
  }
  if (threadIdx.x < (unsigned)nb) bsums[threadIdx.x] = s[threadIdx.x] - v;
}

// level 3: offsets[i] = exclusive scan = incl[i] - counts[i] + bsums[chunk]
__global__ __launch_bounds__(256) void finalize_offsets_kernel(
    const int* __restrict__ incl, const int* __restrict__ counts,
    const int* __restrict__ bsums, int* __restrict__ offsets, int n) {
  int i = blockIdx.x * blockDim.x + threadIdx.x;
  if (i < n) offsets[i] = incl[i] - counts[i] + bsums[i >> 9];
}

// ---------------- pass 3: scatter edges into row-sorted order --------------
__global__ __launch_bounds__(256) void scatter_kernel(
    const int* __restrict__ rows, const int* __restrict__ cols,
    const float* __restrict__ vals, const int* __restrict__ offsets,
    int* __restrict__ cursors, float2* __restrict__ pairs, int E) {
  int e = blockIdx.x * blockDim.x + threadIdx.x;
  if (e >= E) return;
  int r = rows[e];
  int pos = offsets[r] + atomicAdd(&cursors[r], 1);
  pairs[pos] = make_float2(__int_as_float(cols[e]), vals[e]);
}

// ---------------- pass 4: CSR SpMM, one wave per row -----------------------
__global__ __launch_bounds__(256) void spmm_csr_kernel(
    const float2* __restrict__ pairs, const int* __restrict__ offsets,
    const int* __restrict__ counts, const float* __restrict__ b,
    float* __restrict__ out, int N) {
  int t = blockIdx.x * blockDim.x + threadIdx.x;
  int w = t >> 6;   // row
  int d = t & 63;   // output column (lane)
  if (w >= N) return;
  int start = offsets[w];
  int cnt = counts[w];
  float acc = 0.f;
  for (int base = 0; base < cnt; base += 64) {
    int m = cnt - base;
    if (m > 64) m = 64;
    // cooperative load: lane d grabs edge (base+d); broadcast via shuffle
    float2 p = (d < m) ? pairs[start + base + d] : make_float2(0.f, 0.f);
    int pc = __float_as_int(p.x);
    float pv = p.y;
    for (int j = 0; j < m; j++) {
      int c = __shfl(pc, j);
      float v = __shfl(pv, j);
      acc += v * b[(long long)c * D + d];   // coalesced 256B row gather
    }
  }
  out[(long long)w * D + d] = acc;  // single coalesced store, no atomics
}

extern "C" void kernel_launch(void* const* d_in, const int* in_sizes, int n_in,
                              void* d_out, int out_size, void* d_ws, size_t ws_size,
                              hipStream_t stream) {
  const int* indices = (const int*)d_in[0];   // (2, E) int32
  const float* vals  = (const float*)d_in[1]; // (E,)
  const float* b     = (const float*)d_in[3]; // (N, D)

  int E = in_sizes[1];
  int N = in_sizes[3] / D;
  const int* rows = indices;
  const int* cols = indices + E;

  int nblocks_scan = (N + 511) / 512;

  // workspace layout
  size_t off_counts  = 0;
  size_t off_cursors = off_counts  + (size_t)N * 4;
  size_t off_offsets = off_cursors + (size_t)N * 4;
  size_t off_incl    = off_offsets + (size_t)N * 4;
  size_t off_bsums   = off_incl    + (size_t)N * 4;
  size_t off_pairs   = (off_bsums + 256 * 4 + 15) & ~(size_t)15;
  size_t need        = off_pairs + (size_t)E * 8;

  if (ws_size < need || nblocks_scan > 256) {
    // fallback: round-0 atomic kernel
    hipMemsetAsync(d_out, 0, (size_t)out_size * sizeof(float), stream);
    long long total = (long long)E * 64;
    spmm_atomic_kernel<<<(int)((total + 255) / 256), 256, 0, stream>>>(
        rows, cols, vals, b, (float*)d_out, E);
    return;
  }

  char* ws = (char*)d_ws;
  int*    counts  = (int*)(ws + off_counts);
  int*    cursors = (int*)(ws + off_cursors);
  int*    offsets = (int*)(ws + off_offsets);
  int*    incl    = (int*)(ws + off_incl);
  int*    bsums   = (int*)(ws + off_bsums);
  float2* pairs   = (float2*)(ws + off_pairs);

  // zero counts + cursors (contiguous)
  hipMemsetAsync(counts, 0, (size_t)N * 8, stream);

  hist_kernel<<<(E + 255) / 256, 256, 0, stream>>>(rows, counts, E);
  scan_blocks_kernel<<<nblocks_scan, 512, 0, stream>>>(counts, incl, bsums, N);
  scan_sums_kernel<<<1, 256, 0, stream>>>(bsums, nblocks_scan);
  finalize_offsets_kernel<<<(N + 255) / 256, 256, 0, stream>>>(
      incl, counts, bsums, offsets, N);
  scatter_kernel<<<(E + 255) / 256, 256, 0, stream>>>(
      rows, cols, vals, offsets, cursors, pairs, E);
  spmm_csr_kernel<<<(int)(((long long)N * 64 + 255) / 256), 256, 0, stream>>>(
      pairs, offsets, counts, b, (float*)d_out, N);
}